// Round 10
// baseline (165.191 us; speedup 1.0000x reference)
//
#include <hip/hip_runtime.h>
#include <math.h>

// Problem constants (S4Checkpointed): b=2, L=2048, d=768, n=16, r=48
#define BATCH 2
#define LSEQ  2048
#define DIM   768
#define NST   16
#define RDT   48
#define BL    (BATCH*LSEQ)   // 4096
#define NCHUNK 16
#define CLEN   (LSEQ/NCHUNK) // 128
#define NPACK  (CLEN/4)      // 32 float4 packs per chunk
#define LP4    (LSEQ/4)      // 512 t-packs per (b)
#define L2E    1.4426950408889634f

typedef __attribute__((ext_vector_type(8))) short short8;     // 8 bf16 (4 VGPRs)
typedef __attribute__((ext_vector_type(4))) float float4e;    // MFMA acc

__device__ __forceinline__ ushort f2bf(float f) {
    union { float f; unsigned u; } v; v.f = f;
    unsigned u = v.u;
    u += 0x7fffu + ((u >> 16) & 1u);   // round-to-nearest-even
    return (ushort)(u >> 16);
}

// DPP cross-lane add on the VALU pipe (no ds_swizzle).
// 0xB1 = quad_perm xor1; 0x4E = quad_perm xor2; 0x124/0x128 = row_ror:4/8
// (rotation mod 16 preserves n&3 -> exact for our 16-lane row sum).
template <int CTRL>
__device__ __forceinline__ float dpp_add(float v) {
    const int s = __builtin_amdgcn_update_dpp(__float_as_int(v), __float_as_int(v),
                                              CTRL, 0xF, 0xF, false);
    return v + __int_as_float(s);
}

// -------- Kernel P: x transpose (b,l,d)->(b,d,l) + pack W slice to bf16 ----
__global__ __launch_bounds__(256) void pack_kernel(
        const float* __restrict__ x, const float* __restrict__ Wx,
        float* __restrict__ xT, ushort* __restrict__ Wbf) {
    if (blockIdx.y == DIM / 64) {
        const int blk = blockIdx.z * 32 + blockIdx.x;       // 0..63
        for (int idx = blk * 256 + threadIdx.x; idx < 80 * DIM; idx += 64 * 256) {
            const int j = idx / DIM;
            const int k = idx - j * DIM;
            const int row = (j < 16) ? j : ((j < 32) ? (j + 16) : (j + 1552));
            Wbf[idx] = f2bf(Wx[(size_t)row * DIM + k]);
        }
        return;
    }
    __shared__ float tile[64 * 65];   // stored transposed: tile[c][r]
    const int r0 = blockIdx.x * 64;   // l
    const int c0 = blockIdx.y * 64;   // d
    const int b  = blockIdx.z;
    const int tid = threadIdx.x;
    {
        const int c4 = tid & 15, rb = tid >> 4;
        #pragma unroll
        for (int rr = 0; rr < 4; ++rr) {
            const int row = rr * 16 + rb;
            const float4 v = *(const float4*)(x + ((size_t)b * LSEQ + r0 + row) * DIM + c0 + c4 * 4);
            tile[(c4 * 4 + 0) * 65 + row] = v.x;
            tile[(c4 * 4 + 1) * 65 + row] = v.y;
            tile[(c4 * 4 + 2) * 65 + row] = v.z;
            tile[(c4 * 4 + 3) * 65 + row] = v.w;
        }
    }
    __syncthreads();
    {
        const int t4 = tid & 15, dq = tid >> 4;
        #pragma unroll
        for (int pass = 0; pass < 4; ++pass) {
            const int dd = pass * 16 + dq;
            float4 v;
            v.x = tile[dd * 65 + t4 * 4 + 0];
            v.y = tile[dd * 65 + t4 * 4 + 1];
            v.z = tile[dd * 65 + t4 * 4 + 2];
            v.w = tile[dd * 65 + t4 * 4 + 3];
            *(float4*)(xT + ((size_t)b * DIM + c0 + dd) * LSEQ + r0 + t4 * 4) = v;
        }
    }
}

// -------- Kernel G: proj GEMM via MFMA, 5 waves/block (one per N-tile) ------
// M=4096 (bl), N=80 (16 B | 16 C | 48 dt), K=768. Block = 5 waves; wave nt
// computes M-tile x N-tile nt, K=768 = 24 x mfma_f32_16x16x32_bf16.
// A (x rows) loads shared across the 5 waves via L1. fp32 -> bf16 in-register.
__global__ __launch_bounds__(320) void proj_gemm_kernel(
        const float* __restrict__ x, const ushort* __restrict__ Wbf,
        float* __restrict__ Bpk, float* __restrict__ Cpk,
        float* __restrict__ dtpT) {
    const int m0   = blockIdx.x * 16;   // bl tile base (never straddles b)
    const int nt   = threadIdx.x >> 6;  // 0..4 (N-tile)
    const int lane = threadIdx.x & 63;
    const int col  = lane & 15;
    const int quad = lane >> 4;

    const float* A  = x + (size_t)(m0 + col) * DIM + quad * 8;
    const short* Bw = (const short*)Wbf + (size_t)(nt * 16 + col) * DIM + quad * 8;

    float4e acc = {};
    #pragma unroll 4
    for (int kk = 0; kk < 24; ++kk) {
        const float4 a0 = *(const float4*)(A + kk * 32);
        const float4 a1 = *(const float4*)(A + kk * 32 + 4);
        short8 a;
        a[0] = (short)f2bf(a0.x); a[1] = (short)f2bf(a0.y);
        a[2] = (short)f2bf(a0.z); a[3] = (short)f2bf(a0.w);
        a[4] = (short)f2bf(a1.x); a[5] = (short)f2bf(a1.y);
        a[6] = (short)f2bf(a1.z); a[7] = (short)f2bf(a1.w);
        const short8 bf = *(const short8*)(Bw + kk * 32);
        acc = __builtin_amdgcn_mfma_f32_16x16x32_bf16(a, bf, acc, 0, 0, 0);
    }

    const int b  = m0 >> 11;
    const int t0 = m0 & 2047;
    if (nt == 0) {
        ((float4*)Bpk)[((size_t)(b * LP4 + (t0 >> 2) + quad)) * NST + col] = *(float4*)&acc;
    } else if (nt == 1) {
        ((float4*)Cpk)[((size_t)(b * LP4 + (t0 >> 2) + quad)) * NST + col] = *(float4*)&acc;
    } else {
        const int r = (nt - 2) * 16 + col;
        *(float4*)(dtpT + ((size_t)(b * RDT + r)) * LSEQ + t0 + quad * 4) = *(float4*)&acc;
    }
}

// -------- Kernel C: fused delta + chunked scan -----------------------------
// 256 threads (4 waves) per (b,d); LDS ~10.4 KB -> 6 blocks/CU -> ALL 1536
// blocks co-resident (single round). 16 chunks x 16 n-lanes; chunk g owns
// 128 t. x read as wave-broadcast float4 from global (L2-hot row). Phase 3
// folds +D*x and writes y straight to global yv (aliases xT; per-thread
// load-before-store, disjoint 16B regions). silu(z) applied in xpose_out.
__global__ __launch_bounds__(256) void scan_kernel(
        const float* __restrict__ xT, const float* __restrict__ A_log,
        const float* __restrict__ Dp,
        const float* __restrict__ Bpk, const float* __restrict__ Cpk,
        const float* __restrict__ dtpT, const float* __restrict__ Wdt,
        const float* __restrict__ bdt, float* __restrict__ yv) {
    __shared__ float sdel[LSEQ];        // 8 KB (delta, no pad: hot reads are broadcast)
    __shared__ float sP[NCHUNK][NST];   // 1 KB
    __shared__ float sq[NCHUNK][NST];   // 1 KB
    __shared__ float sw[RDT];

    const int tid = threadIdx.x;
    const int ch = blockIdx.x;           // b*768 + d
    const int b = ch / DIM;
    const int d = ch % DIM;
    const size_t row = (size_t)ch * LSEQ;

    if (tid < RDT) sw[tid] = Wdt[(size_t)d * RDT + tid];
    __syncthreads();

    // ---- phase 0: fused delta -> sdel (thread owns 2 float4 t-columns)
    {
        const float bb = 2.0f * bdt[d];
        const float* dbase = dtpT + (size_t)b * RDT * LSEQ;
        #pragma unroll
        for (int i = 0; i < 2; ++i) {
            const int idx = tid + 256 * i;
            float4 acc = make_float4(bb, bb, bb, bb);
            #pragma unroll 3
            for (int k4 = 0; k4 < RDT / 4; ++k4) {
                const float4 wv = ((const float4*)sw)[k4];
                #pragma unroll
                for (int j = 0; j < 4; ++j) {
                    const int k = k4 * 4 + j;
                    const float wk = (j == 0) ? wv.x : (j == 1) ? wv.y : (j == 2) ? wv.z : wv.w;
                    const float4 v = ((const float4*)(dbase + (size_t)k * LSEQ))[idx];
                    acc.x = fmaf(v.x, wk, acc.x);
                    acc.y = fmaf(v.y, wk, acc.y);
                    acc.z = fmaf(v.z, wk, acc.z);
                    acc.w = fmaf(v.w, wk, acc.w);
                }
            }
            float4 sp;
            sp.x = (acc.x > 20.f) ? acc.x : __logf(1.f + __expf(acc.x));
            sp.y = (acc.y > 20.f) ? acc.y : __logf(1.f + __expf(acc.y));
            sp.z = (acc.z > 20.f) ? acc.z : __logf(1.f + __expf(acc.z));
            sp.w = (acc.w > 20.f) ? acc.w : __logf(1.f + __expf(acc.w));
            ((float4*)sdel)[idx] = sp;
        }
    }
    __syncthreads();

    const int g = tid >> 4;          // chunk 0..15
    const int n = tid & 15;          // state index
    const float Aln2 = -__expf(A_log[d * NST + n]) * L2E;  // exp(x)=exp2(x*L2E)
    const float4* Bg = (const float4*)Bpk + ((size_t)(b * LP4 + g * NPACK) * NST + n);
    const float4* Cg = (const float4*)Cpk + ((size_t)(b * LP4 + g * NPACK) * NST + n);
    const float4* xr = (const float4*)(xT + row) + g * NPACK;   // broadcast reads

    // ---- phase 1: local scan with pack trick (chain: 1 fma per 4t)
    {
        float h = 0.f, Ptot = 1.f;
        float4 Bn_ = Bg[0], xn_ = xr[0];
        #pragma unroll 4
        for (int p = 0; p < NPACK; ++p) {
            const float4 B4 = Bn_, x4 = xn_;
            if (p < NPACK - 1) { Bn_ = Bg[(p + 1) * NST]; xn_ = xr[p + 1]; }
            const float4 dl = ((const float4*)sdel)[g * NPACK + p];
            const float u0 = dl.x * x4.x * B4.x, u1 = dl.y * x4.y * B4.y;
            const float u2 = dl.z * x4.z * B4.z, u3 = dl.w * x4.w * B4.w;
            const float e0  = __builtin_amdgcn_exp2f(Aln2 * dl.x);
            const float dA1 = __builtin_amdgcn_exp2f(Aln2 * dl.y);
            const float dA2 = __builtin_amdgcn_exp2f(Aln2 * dl.z);
            const float dA3 = __builtin_amdgcn_exp2f(Aln2 * dl.w);
            float s = u0;
            s = fmaf(dA1, s, u1); s = fmaf(dA2, s, u2); s = fmaf(dA3, s, u3);
            const float E3 = ((e0 * dA1) * (dA2 * dA3));
            h = fmaf(E3, h, s);          // the only cross-pack chain op
            Ptot *= E3;
        }
        sP[g][n] = Ptot;
        sq[g][n] = h;
    }
    __syncthreads();

    // ---- phase 2: Kogge-Stone inclusive scan over 16 chunks (4 steps)
    {
        float Pc = sP[g][n], qc = sq[g][n];
        #pragma unroll
        for (int s = 1; s < NCHUNK; s <<= 1) {
            float Pp = 1.f, qp = 0.f;
            if (g >= s) { Pp = sP[g - s][n]; qp = sq[g - s][n]; }
            __syncthreads();
            qc = fmaf(Pc, qp, qc);
            Pc *= Pp;
            sP[g][n] = Pc; sq[g][n] = qc;
            __syncthreads();
        }
    }

    // ---- phase 3: re-scan with carry; DPP n-reduction; y -> global (+D*x)
    {
        float h = (g == 0) ? 0.f : sq[g - 1][n];
        const float Dd = Dp[d];
        float4 Bn_ = Bg[0], Cn_ = Cg[0], xn_ = xr[0];
        #pragma unroll 4
        for (int p = 0; p < NPACK; ++p) {
            const float4 B4 = Bn_, C4 = Cn_, x4 = xn_;
            if (p < NPACK - 1) { Bn_ = Bg[(p + 1) * NST]; Cn_ = Cg[(p + 1) * NST]; xn_ = xr[p + 1]; }
            const float4 dl = ((const float4*)sdel)[g * NPACK + p];
            const float u0 = dl.x * x4.x * B4.x, u1 = dl.y * x4.y * B4.y;
            const float u2 = dl.z * x4.z * B4.z, u3 = dl.w * x4.w * B4.w;
            const float E0  = __builtin_amdgcn_exp2f(Aln2 * dl.x);
            const float dA1 = __builtin_amdgcn_exp2f(Aln2 * dl.y);
            const float dA2 = __builtin_amdgcn_exp2f(Aln2 * dl.z);
            const float dA3 = __builtin_amdgcn_exp2f(Aln2 * dl.w);
            const float E1 = E0 * dA1, E2 = E1 * dA2, E3 = E2 * dA3;
            const float s0 = u0;
            const float s1 = fmaf(dA1, s0, u1);
            const float s2 = fmaf(dA2, s1, u2);
            const float s3 = fmaf(dA3, s2, u3);
            const float h0 = fmaf(E0, h, s0);
            const float h1 = fmaf(E1, h, s1);
            const float h2 = fmaf(E2, h, s2);
            const float h3 = fmaf(E3, h, s3);
            h = h3;                      // 1-fma cross-pack chain
            float p0 = h0 * C4.x, p1 = h1 * C4.y, p2 = h2 * C4.z, p3 = h3 * C4.w;
            p0 = dpp_add<0xB1>(p0); p0 = dpp_add<0x4E>(p0);   // quad sums
            p1 = dpp_add<0xB1>(p1); p1 = dpp_add<0x4E>(p1);
            p2 = dpp_add<0xB1>(p2); p2 = dpp_add<0x4E>(p2);
            p3 = dpp_add<0xB1>(p3); p3 = dpp_add<0x4E>(p3);
            float v = (n & 1) ? ((n & 2) ? p3 : p1) : ((n & 2) ? p2 : p0);
            v = dpp_add<0x124>(v);       // row_ror:4
            v = dpp_add<0x128>(v);       // row_ror:8
            if (n < 4) {                 // lane n holds total for t = 4p+n
                const float xc = (n == 0) ? x4.x : (n == 1) ? x4.y : (n == 2) ? x4.z : x4.w;
                yv[row + g * CLEN + 4 * p + n] = fmaf(xc, Dd, v);
            }
        }
    }
}

// -------- Kernel T: output transpose + silu(z) epilogue --------------------
// yv and z are both (b,d,l); out = yv * z*sigmoid(z), transposed to (b,l,d).
__global__ __launch_bounds__(256) void xpose_out_kernel(
        const float* __restrict__ yv, const float* __restrict__ z,
        float* __restrict__ out) {
    __shared__ float tile[64 * 65];   // transposed: tile[l][d]
    const int r0 = blockIdx.x * 64;   // d
    const int c0 = blockIdx.y * 64;   // l
    const int b  = blockIdx.z;
    const int tid = threadIdx.x;
    {
        const int c4 = tid & 15, rb = tid >> 4;
        #pragma unroll
        for (int rr = 0; rr < 4; ++rr) {
            const int row = rr * 16 + rb;
            const size_t gidx = ((size_t)b * DIM + r0 + row) * LSEQ + c0 + c4 * 4;
            const float4 v = *(const float4*)(yv + gidx);
            const float4 zv = *(const float4*)(z + gidx);
            tile[(c4 * 4 + 0) * 65 + row] = v.x * zv.x / (1.f + __expf(-zv.x));
            tile[(c4 * 4 + 1) * 65 + row] = v.y * zv.y / (1.f + __expf(-zv.y));
            tile[(c4 * 4 + 2) * 65 + row] = v.z * zv.z / (1.f + __expf(-zv.z));
            tile[(c4 * 4 + 3) * 65 + row] = v.w * zv.w / (1.f + __expf(-zv.w));
        }
    }
    __syncthreads();
    {
        const int t4 = tid & 15, dq = tid >> 4;
        #pragma unroll
        for (int pass = 0; pass < 4; ++pass) {
            const int ll = pass * 16 + dq;
            float4 v;
            v.x = tile[ll * 65 + t4 * 4 + 0];
            v.y = tile[ll * 65 + t4 * 4 + 1];
            v.z = tile[ll * 65 + t4 * 4 + 2];
            v.w = tile[ll * 65 + t4 * 4 + 3];
            *(float4*)(out + ((size_t)b * LSEQ + c0 + ll) * DIM + r0 + t4 * 4) = v;
        }
    }
}

extern "C" void kernel_launch(void* const* d_in, const int* in_sizes, int n_in,
                              void* d_out, int out_size, void* d_ws, size_t ws_size,
                              hipStream_t stream) {
    const float* x     = (const float*)d_in[0];  // (2,2048,768)
    const float* z     = (const float*)d_in[1];  // (2,768,2048)
    const float* A_log = (const float*)d_in[2];  // (768,16)
    const float* D     = (const float*)d_in[3];  // (768,)
    const float* Wx    = (const float*)d_in[4];  // (1680,768)
    const float* Wdt   = (const float*)d_in[5];  // (768,48)
    const float* bdt   = (const float*)d_in[6];  // (768,)
    float* out = (float*)d_out;

    // ws layout (floats): Bpk | Cpk | dtpT | xT (scan writes yv over it) | Wbf(bf16)
    float* ws    = (float*)d_ws;
    float* Bpk   = ws;
    float* Cpk   = Bpk + (size_t)BATCH * LP4 * NST * 4;
    float* dtpT  = Cpk + (size_t)BATCH * LP4 * NST * 4;
    float* xT    = dtpT + (size_t)BATCH * RDT * LSEQ;
    float* yv    = xT;   // alias: scan's per-thread read precedes its write, regions disjoint
    ushort* Wbf  = (ushort*)(xT + (size_t)BATCH * DIM * LSEQ);

    hipLaunchKernelGGL(pack_kernel, dim3(LSEQ / 64, DIM / 64 + 1, BATCH), dim3(256), 0, stream,
                       x, Wx, xT, Wbf);
    hipLaunchKernelGGL(proj_gemm_kernel, dim3(BL / 16), dim3(320), 0, stream,
                       x, Wbf, Bpk, Cpk, dtpT);
    hipLaunchKernelGGL(scan_kernel, dim3(BATCH * DIM), dim3(256), 0, stream,
                       xT, A_log, D, Bpk, Cpk, dtpT, Wdt, bdt, yv);
    hipLaunchKernelGGL(xpose_out_kernel, dim3(DIM / 64, LSEQ / 64, BATCH), dim3(256), 0, stream,
                       yv, z, out);
}

// Round 11
// 152.543 us; speedup vs baseline: 1.0829x; 1.0829x over previous
//
#include <hip/hip_runtime.h>
#include <math.h>

// Problem constants (S4Checkpointed): b=2, L=2048, d=768, n=16, r=48
#define BATCH 2
#define LSEQ  2048
#define DIM   768
#define NST   16
#define RDT   48
#define BL    (BATCH*LSEQ)   // 4096
#define NCHUNK 32
#define CLEN   (LSEQ/NCHUNK) // 64
#define CPAD   68            // chunk stride floats: 68%32==4 -> wave's 4 groups on distinct banks
#define NPACK  (CLEN/4)      // 16 float4 packs per chunk
#define LP4    (LSEQ/4)      // 512 t-packs per (b)
#define L2E    1.4426950408889634f

typedef __attribute__((ext_vector_type(8))) short short8;     // 8 bf16 (4 VGPRs)
typedef __attribute__((ext_vector_type(4))) float float4e;    // MFMA acc

__device__ __forceinline__ ushort f2bf(float f) {
    union { float f; unsigned u; } v; v.f = f;
    unsigned u = v.u;
    u += 0x7fffu + ((u >> 16) & 1u);   // round-to-nearest-even
    return (ushort)(u >> 16);
}

// DPP cross-lane add on the VALU pipe (no ds_swizzle).
// 0xB1 = quad_perm xor1; 0x4E = quad_perm xor2; 0x124/0x128 = row_ror:4/8
// (rotation mod 16 preserves n&3 -> exact for our 16-lane row sum).
template <int CTRL>
__device__ __forceinline__ float dpp_add(float v) {
    const int s = __builtin_amdgcn_update_dpp(__float_as_int(v), __float_as_int(v),
                                              CTRL, 0xF, 0xF, false);
    return v + __int_as_float(s);
}

// -------- Kernel W: pack weights to bf16 -----------------------------------
// Wbf: 80 live W_xproj rows [B:0..15 | C:32..47 | dt:1584..1631], 80x768.
// Wdtbf: Wdt (768x48) zero-padded to 768x64 for two K=32 MFMAs.
__global__ __launch_bounds__(256) void wpack_kernel(
        const float* __restrict__ Wx, const float* __restrict__ Wdt,
        ushort* __restrict__ Wbf, ushort* __restrict__ Wdtbf) {
    const int tid0 = blockIdx.x * 256 + threadIdx.x;
    for (int i = tid0; i < 80 * DIM; i += gridDim.x * 256) {
        const int j = i / DIM;
        const int k = i - j * DIM;
        const int row = (j < 16) ? j : ((j < 32) ? (j + 16) : (j + 1552));
        Wbf[i] = f2bf(Wx[(size_t)row * DIM + k]);
    }
    for (int i = tid0; i < DIM * 64; i += gridDim.x * 256) {
        const int dd = i >> 6;
        const int k = i & 63;
        Wdtbf[i] = (k < RDT) ? f2bf(Wdt[dd * RDT + k]) : (ushort)0;
    }
}

// -------- Kernel G: proj GEMM + delta GEMM + xT emit (MFMA) ----------------
// Block = 5 waves, one 16-row bl-tile. Pass 1: proj (M=16 bl, N=80, K=768),
// wave nt owns N-tile nt; wave 0 also stores the x rows transposed to xT.
// dt-waves (nt>=2) drop their dtp tiles into LDS. Pass 2: delta GEMM
// (M=16 t, N=768 d, K=48->64) over 48 d-tiles round-robin across 5 waves;
// epilogue softplus(. + 2*bdt) -> deltaT (b,d,l) coalesced float4.
__global__ __launch_bounds__(320) void proj_gemm_kernel(
        const float* __restrict__ x, const ushort* __restrict__ Wbf,
        const ushort* __restrict__ Wdtbf, const float* __restrict__ bdt,
        float* __restrict__ Bpk, float* __restrict__ Cpk,
        float* __restrict__ deltaT, float* __restrict__ xT) {
    __shared__ float dtp_s[16 * 65];    // [t][r], stride 65 (conflict-free frag reads)
    const int m0   = blockIdx.x * 16;   // bl tile base (never straddles b)
    const int nt   = threadIdx.x >> 6;  // 0..4 (N-tile / wave)
    const int lane = threadIdx.x & 63;
    const int col  = lane & 15;
    const int quad = lane >> 4;
    const int b  = m0 >> 11;
    const int t0 = m0 & 2047;

    for (int i = threadIdx.x; i < 16 * 65; i += 320) dtp_s[i] = 0.f;
    __syncthreads();

    const float* A  = x + (size_t)(m0 + col) * DIM + quad * 8;
    const short* Bw = (const short*)Wbf + (size_t)(nt * 16 + col) * DIM + quad * 8;

    float4e acc = {};
    #pragma unroll 4
    for (int kk = 0; kk < 24; ++kk) {
        const float4 a0 = *(const float4*)(A + kk * 32);
        const float4 a1 = *(const float4*)(A + kk * 32 + 4);
        short8 a;
        a[0] = (short)f2bf(a0.x); a[1] = (short)f2bf(a0.y);
        a[2] = (short)f2bf(a0.z); a[3] = (short)f2bf(a0.w);
        a[4] = (short)f2bf(a1.x); a[5] = (short)f2bf(a1.y);
        a[6] = (short)f2bf(a1.z); a[7] = (short)f2bf(a1.w);
        if (nt == 0) {   // emit xT: 16 lanes of a quarter-row span 16 consecutive t
            const int dbase = kk * 32 + quad * 8;
            float* xc = xT + ((size_t)(b * DIM + dbase)) * LSEQ + t0 + col;
            xc[0 * LSEQ] = a0.x; xc[1 * LSEQ] = a0.y;
            xc[2 * LSEQ] = a0.z; xc[3 * LSEQ] = a0.w;
            xc[4 * LSEQ] = a1.x; xc[5 * LSEQ] = a1.y;
            xc[6 * LSEQ] = a1.z; xc[7 * LSEQ] = a1.w;
        }
        const short8 bf = *(const short8*)(Bw + kk * 32);
        acc = __builtin_amdgcn_mfma_f32_16x16x32_bf16(a, bf, acc, 0, 0, 0);
    }

    if (nt == 0) {
        ((float4*)Bpk)[((size_t)(b * LP4 + (t0 >> 2) + quad)) * NST + col] = *(float4*)&acc;
    } else if (nt == 1) {
        ((float4*)Cpk)[((size_t)(b * LP4 + (t0 >> 2) + quad)) * NST + col] = *(float4*)&acc;
    } else {            // dtp tile -> LDS: t_local = quad*4+reg, r = (nt-2)*16+col
        #pragma unroll
        for (int r = 0; r < 4; ++r)
            dtp_s[(quad * 4 + r) * 65 + (nt - 2) * 16 + col] = acc[r];
    }
    __syncthreads();

    // ---- delta GEMM: A-frag (same for all d-tiles) hoisted
    short8 da0, da1;
    #pragma unroll
    for (int j = 0; j < 8; ++j) {
        da0[j] = (short)f2bf(dtp_s[col * 65 + quad * 8 + j]);
        da1[j] = (short)f2bf(dtp_s[col * 65 + 32 + quad * 8 + j]);
    }
    for (int dt = nt; dt < 48; dt += 5) {
        const int d0 = dt * 16;
        const short8 b0 = *(const short8*)((const short*)Wdtbf + (size_t)(d0 + col) * 64 + quad * 8);
        const short8 b1 = *(const short8*)((const short*)Wdtbf + (size_t)(d0 + col) * 64 + 32 + quad * 8);
        float4e dacc = {};
        dacc = __builtin_amdgcn_mfma_f32_16x16x32_bf16(da0, b0, dacc, 0, 0, 0);
        dacc = __builtin_amdgcn_mfma_f32_16x16x32_bf16(da1, b1, dacc, 0, 0, 0);
        const float bb = 2.0f * bdt[d0 + col];
        float4 sp;
        {
            const float v0 = dacc[0] + bb, v1 = dacc[1] + bb;
            const float v2 = dacc[2] + bb, v3 = dacc[3] + bb;
            sp.x = (v0 > 20.f) ? v0 : __logf(1.f + __expf(v0));
            sp.y = (v1 > 20.f) ? v1 : __logf(1.f + __expf(v1));
            sp.z = (v2 > 20.f) ? v2 : __logf(1.f + __expf(v2));
            sp.w = (v3 > 20.f) ? v3 : __logf(1.f + __expf(v3));
        }
        *(float4*)(deltaT + ((size_t)(b * DIM + d0 + col)) * LSEQ + t0 + quad * 4) = sp;
    }
}

// -------- Kernel C: chunked scan (pack-trick, Kogge-Stone, DPP) ------------
// 512 thr per (b,d); LDS 12.9 KB -> 4 blocks/CU (32 waves, wave-capped).
// 32 chunks x 16 n-lanes; chunk g owns 64 t. delta from LDS (padded, proven
// conflict-free); x/B/C from global with one-pack prefetch. Phase 3 folds
// +D*x and writes y straight to global (aliases xT; in-wave load-before-store
// on disjoint rows -> race-free). silu(z) applied in xpose_out.
__global__ __launch_bounds__(512) void scan_kernel(
        const float* __restrict__ xT, const float* __restrict__ A_log,
        const float* __restrict__ Dp,
        const float* __restrict__ Bpk, const float* __restrict__ Cpk,
        const float* __restrict__ deltaT, float* __restrict__ yv) {
    __shared__ float sdel[NCHUNK * CPAD];   // 8704 B
    __shared__ float sP[NCHUNK][NST];       // 2 KB
    __shared__ float sq[NCHUNK][NST];       // 2 KB

    const int tid = threadIdx.x;
    const int ch = blockIdx.x;           // b*768 + d
    const int b = ch / DIM;
    const int d = ch % DIM;
    const size_t row = (size_t)ch * LSEQ;

    // ---- phase 0: stage delta row (coalesced, padded chunks)
    {
        const float4 dv4 = ((const float4*)(deltaT + row))[tid];
        ((float4*)sdel)[(tid >> 4) * (CPAD / 4) + (tid & 15)] = dv4;
    }
    __syncthreads();

    const int g = tid >> 4;          // chunk 0..31
    const int n = tid & 15;          // state index
    const float Aln2 = -__expf(A_log[d * NST + n]) * L2E;  // exp(x)=exp2(x*L2E)
    const float4* Bg = (const float4*)Bpk + ((size_t)(b * LP4 + g * NPACK) * NST + n);
    const float4* Cg = (const float4*)Cpk + ((size_t)(b * LP4 + g * NPACK) * NST + n);
    const float4* xr = (const float4*)(xT + row) + g * NPACK;   // broadcast reads
    const float* dchunk = sdel + g * CPAD;

    // ---- phase 1: local scan with pack trick (chain: 1 fma per 4t)
    {
        float h = 0.f, Ptot = 1.f;
        float4 Bn_ = Bg[0], xn_ = xr[0];
        #pragma unroll 4
        for (int p = 0; p < NPACK; ++p) {
            const float4 B4 = Bn_, x4 = xn_;
            if (p < NPACK - 1) { Bn_ = Bg[(p + 1) * NST]; xn_ = xr[p + 1]; }
            const float4 dl = *(const float4*)(dchunk + 4 * p);
            const float u0 = dl.x * x4.x * B4.x, u1 = dl.y * x4.y * B4.y;
            const float u2 = dl.z * x4.z * B4.z, u3 = dl.w * x4.w * B4.w;
            const float e0  = __builtin_amdgcn_exp2f(Aln2 * dl.x);
            const float dA1 = __builtin_amdgcn_exp2f(Aln2 * dl.y);
            const float dA2 = __builtin_amdgcn_exp2f(Aln2 * dl.z);
            const float dA3 = __builtin_amdgcn_exp2f(Aln2 * dl.w);
            float s = u0;
            s = fmaf(dA1, s, u1); s = fmaf(dA2, s, u2); s = fmaf(dA3, s, u3);
            const float E3 = ((e0 * dA1) * (dA2 * dA3));
            h = fmaf(E3, h, s);          // the only cross-pack chain op
            Ptot *= E3;
        }
        sP[g][n] = Ptot;
        sq[g][n] = h;
    }
    __syncthreads();

    // ---- phase 2: Kogge-Stone inclusive scan over 32 chunks (5 steps)
    {
        float Pc = sP[g][n], qc = sq[g][n];
        #pragma unroll
        for (int s = 1; s < NCHUNK; s <<= 1) {
            float Pp = 1.f, qp = 0.f;
            if (g >= s) { Pp = sP[g - s][n]; qp = sq[g - s][n]; }
            __syncthreads();
            qc = fmaf(Pc, qp, qc);
            Pc *= Pp;
            sP[g][n] = Pc; sq[g][n] = qc;
            __syncthreads();
        }
    }

    // ---- phase 3: re-scan with carry; DPP n-reduction; y -> global (+D*x)
    {
        float h = (g == 0) ? 0.f : sq[g - 1][n];
        const float Dd = Dp[d];
        float4 Bn_ = Bg[0], Cn_ = Cg[0], xn_ = xr[0];
        #pragma unroll 4
        for (int p = 0; p < NPACK; ++p) {
            const float4 B4 = Bn_, C4 = Cn_, x4 = xn_;
            if (p < NPACK - 1) { Bn_ = Bg[(p + 1) * NST]; Cn_ = Cg[(p + 1) * NST]; xn_ = xr[p + 1]; }
            const float4 dl = *(const float4*)(dchunk + 4 * p);
            const float u0 = dl.x * x4.x * B4.x, u1 = dl.y * x4.y * B4.y;
            const float u2 = dl.z * x4.z * B4.z, u3 = dl.w * x4.w * B4.w;
            const float E0  = __builtin_amdgcn_exp2f(Aln2 * dl.x);
            const float dA1 = __builtin_amdgcn_exp2f(Aln2 * dl.y);
            const float dA2 = __builtin_amdgcn_exp2f(Aln2 * dl.z);
            const float dA3 = __builtin_amdgcn_exp2f(Aln2 * dl.w);
            const float E1 = E0 * dA1, E2 = E1 * dA2, E3 = E2 * dA3;
            const float s0 = u0;
            const float s1 = fmaf(dA1, s0, u1);
            const float s2 = fmaf(dA2, s1, u2);
            const float s3 = fmaf(dA3, s2, u3);
            const float h0 = fmaf(E0, h, s0);
            const float h1 = fmaf(E1, h, s1);
            const float h2 = fmaf(E2, h, s2);
            const float h3 = fmaf(E3, h, s3);
            h = h3;                      // 1-fma cross-pack chain
            float p0 = h0 * C4.x, p1 = h1 * C4.y, p2 = h2 * C4.z, p3 = h3 * C4.w;
            p0 = dpp_add<0xB1>(p0); p0 = dpp_add<0x4E>(p0);   // quad sums
            p1 = dpp_add<0xB1>(p1); p1 = dpp_add<0x4E>(p1);
            p2 = dpp_add<0xB1>(p2); p2 = dpp_add<0x4E>(p2);
            p3 = dpp_add<0xB1>(p3); p3 = dpp_add<0x4E>(p3);
            float v = (n & 1) ? ((n & 2) ? p3 : p1) : ((n & 2) ? p2 : p0);
            v = dpp_add<0x124>(v);       // row_ror:4
            v = dpp_add<0x128>(v);       // row_ror:8
            if (n < 4) {                 // lane n holds total for t = 4p+n
                const float xc = (n == 0) ? x4.x : (n == 1) ? x4.y : (n == 2) ? x4.z : x4.w;
                yv[row + g * CLEN + 4 * p + n] = fmaf(xc, Dd, v);
            }
        }
    }
}

// -------- Kernel T: output transpose + silu(z) epilogue --------------------
// yv and z are both (b,d,l); out = yv * z*sigmoid(z), transposed to (b,l,d).
__global__ __launch_bounds__(256) void xpose_out_kernel(
        const float* __restrict__ yv, const float* __restrict__ z,
        float* __restrict__ out) {
    __shared__ float tile[64 * 65];   // transposed: tile[l][d]
    const int r0 = blockIdx.x * 64;   // d
    const int c0 = blockIdx.y * 64;   // l
    const int b  = blockIdx.z;
    const int tid = threadIdx.x;
    {
        const int c4 = tid & 15, rb = tid >> 4;
        #pragma unroll
        for (int rr = 0; rr < 4; ++rr) {
            const int row = rr * 16 + rb;
            const size_t gidx = ((size_t)b * DIM + r0 + row) * LSEQ + c0 + c4 * 4;
            const float4 v = *(const float4*)(yv + gidx);
            const float4 zv = *(const float4*)(z + gidx);
            tile[(c4 * 4 + 0) * 65 + row] = v.x * zv.x / (1.f + __expf(-zv.x));
            tile[(c4 * 4 + 1) * 65 + row] = v.y * zv.y / (1.f + __expf(-zv.y));
            tile[(c4 * 4 + 2) * 65 + row] = v.z * zv.z / (1.f + __expf(-zv.z));
            tile[(c4 * 4 + 3) * 65 + row] = v.w * zv.w / (1.f + __expf(-zv.w));
        }
    }
    __syncthreads();
    {
        const int t4 = tid & 15, dq = tid >> 4;
        #pragma unroll
        for (int pass = 0; pass < 4; ++pass) {
            const int ll = pass * 16 + dq;
            float4 v;
            v.x = tile[ll * 65 + t4 * 4 + 0];
            v.y = tile[ll * 65 + t4 * 4 + 1];
            v.z = tile[ll * 65 + t4 * 4 + 2];
            v.w = tile[ll * 65 + t4 * 4 + 3];
            *(float4*)(out + ((size_t)b * LSEQ + c0 + ll) * DIM + r0 + t4 * 4) = v;
        }
    }
}

extern "C" void kernel_launch(void* const* d_in, const int* in_sizes, int n_in,
                              void* d_out, int out_size, void* d_ws, size_t ws_size,
                              hipStream_t stream) {
    const float* x     = (const float*)d_in[0];  // (2,2048,768)
    const float* z     = (const float*)d_in[1];  // (2,768,2048)
    const float* A_log = (const float*)d_in[2];  // (768,16)
    const float* D     = (const float*)d_in[3];  // (768,)
    const float* Wx    = (const float*)d_in[4];  // (1680,768)
    const float* Wdt   = (const float*)d_in[5];  // (768,48)
    const float* bdt   = (const float*)d_in[6];  // (768,)
    float* out = (float*)d_out;

    // ws layout (floats): Bpk | Cpk | deltaT | xT (scan writes yv over it) |
    //                     Wbf (80x768 bf16) | Wdtbf (768x64 bf16)
    float* ws     = (float*)d_ws;
    float* Bpk    = ws;
    float* Cpk    = Bpk + (size_t)BATCH * LP4 * NST * 4;
    float* deltaT = Cpk + (size_t)BATCH * LP4 * NST * 4;
    float* xT     = deltaT + (size_t)BATCH * DIM * LSEQ;
    float* yv     = xT;   // alias: in-wave load-before-store, rows disjoint per block
    ushort* Wbf   = (ushort*)(xT + (size_t)BATCH * DIM * LSEQ);
    ushort* Wdtbf = Wbf + (size_t)80 * DIM;

    hipLaunchKernelGGL(wpack_kernel, dim3(64), dim3(256), 0, stream,
                       Wx, Wdt, Wbf, Wdtbf);
    hipLaunchKernelGGL(proj_gemm_kernel, dim3(BL / 16), dim3(320), 0, stream,
                       x, Wbf, Wdtbf, bdt, Bpk, Cpk, deltaT, xT);
    hipLaunchKernelGGL(scan_kernel, dim3(BATCH * DIM), dim3(512), 0, stream,
                       xT, A_log, D, Bpk, Cpk, deltaT, yv);
    hipLaunchKernelGGL(xpose_out_kernel, dim3(DIM / 64, LSEQ / 64, BATCH), dim3(256), 0, stream,
                       yv, z, out);
}

// Round 12
// 147.628 us; speedup vs baseline: 1.1190x; 1.0333x over previous
//
#include <hip/hip_runtime.h>
#include <math.h>

// Problem constants (S4Checkpointed): b=2, L=2048, d=768, n=16, r=48
#define BATCH 2
#define LSEQ  2048
#define DIM   768
#define NST   16
#define RDT   48
#define BL    (BATCH*LSEQ)   // 4096
#define NCHUNK 32
#define CLEN   (LSEQ/NCHUNK) // 64
#define CPAD   68            // chunk stride floats: 68%32==4 -> wave's 4 groups on distinct banks
#define NPACK  (CLEN/4)      // 16 float4 packs per chunk
#define LP4    (LSEQ/4)      // 512 t-packs per (b)
#define L2E    1.4426950408889634f

typedef __attribute__((ext_vector_type(8))) short short8;     // 8 bf16 (4 VGPRs)
typedef __attribute__((ext_vector_type(4))) float float4e;    // MFMA acc

__device__ __forceinline__ ushort f2bf(float f) {
    union { float f; unsigned u; } v; v.f = f;
    unsigned u = v.u;
    u += 0x7fffu + ((u >> 16) & 1u);   // round-to-nearest-even
    return (ushort)(u >> 16);
}

// DPP cross-lane add on the VALU pipe (no ds_swizzle).
// 0xB1 = quad_perm xor1; 0x4E = quad_perm xor2; 0x124/0x128 = row_ror:4/8
// (rotation mod 16 preserves n&3 -> exact for our 16-lane row sum).
template <int CTRL>
__device__ __forceinline__ float dpp_add(float v) {
    const int s = __builtin_amdgcn_update_dpp(__float_as_int(v), __float_as_int(v),
                                              CTRL, 0xF, 0xF, false);
    return v + __int_as_float(s);
}

__device__ __forceinline__ short8 cvt8(float4 a, float4 b) {
    short8 r;
    r[0] = (short)f2bf(a.x); r[1] = (short)f2bf(a.y);
    r[2] = (short)f2bf(a.z); r[3] = (short)f2bf(a.w);
    r[4] = (short)f2bf(b.x); r[5] = (short)f2bf(b.y);
    r[6] = (short)f2bf(b.z); r[7] = (short)f2bf(b.w);
    return r;
}

// -------- Kernel G: proj GEMM + delta GEMM + xT emit (MFMA, fp32 loads) ----
// Block = 5 waves, one 16-row bl-tile. Pass 1: proj (M=16 bl, N=80, K=768);
// wave nt owns N-tile nt. W loaded fp32 + in-register bf16 cvt (wpack kernel
// eliminated). xT emit balanced across all 5 waves (kk ranges 5/5/5/5/4).
// dt-waves (nt>=2) drop dtp tiles into LDS. Pass 2: delta GEMM (M=16 t,
// N=768 d, K=48) round-robin over 48 d-tiles; softplus -> deltaT (b,d,l).
__global__ __launch_bounds__(320) void proj_gemm_kernel(
        const float* __restrict__ x, const float* __restrict__ Wx,
        const float* __restrict__ Wdt, const float* __restrict__ bdt,
        float* __restrict__ Bpk, float* __restrict__ Cpk,
        float* __restrict__ deltaT, float* __restrict__ xT) {
    __shared__ float dtp_s[16 * 65];    // [t][r], stride 65; cols 48..63 stay 0 (A pad)
    const int m0   = blockIdx.x * 16;   // bl tile base (never straddles b)
    const int nt   = threadIdx.x >> 6;  // 0..4 (N-tile / wave)
    const int lane = threadIdx.x & 63;
    const int col  = lane & 15;
    const int quad = lane >> 4;
    const int b  = m0 >> 11;
    const int t0 = m0 & 2047;

    for (int i = threadIdx.x; i < 16 * 65; i += 320) dtp_s[i] = 0.f;
    __syncthreads();

    const int j80  = nt * 16 + col;     // 0..79
    const int wrow = (j80 < 16) ? j80 : ((j80 < 32) ? (j80 + 16) : (j80 + 1552));
    const float* A  = x + (size_t)(m0 + col) * DIM + quad * 8;
    const float* Wr = Wx + (size_t)wrow * DIM + quad * 8;

    const int kklo = nt * 5;                       // xT emit share
    const int kkhi = (nt == 4) ? 24 : (kklo + 5);

    float4e acc = {};
    #pragma unroll 4
    for (int kk = 0; kk < 24; ++kk) {
        const float4 a0 = *(const float4*)(A + kk * 32);
        const float4 a1 = *(const float4*)(A + kk * 32 + 4);
        if (kk >= kklo && kk < kkhi) {   // emit xT: 16 lanes span 16 consecutive t
            const int dbase = kk * 32 + quad * 8;
            float* xc = xT + ((size_t)(b * DIM + dbase)) * LSEQ + t0 + col;
            xc[0 * LSEQ] = a0.x; xc[1 * LSEQ] = a0.y;
            xc[2 * LSEQ] = a0.z; xc[3 * LSEQ] = a0.w;
            xc[4 * LSEQ] = a1.x; xc[5 * LSEQ] = a1.y;
            xc[6 * LSEQ] = a1.z; xc[7 * LSEQ] = a1.w;
        }
        const float4 w0 = *(const float4*)(Wr + kk * 32);
        const float4 w1 = *(const float4*)(Wr + kk * 32 + 4);
        acc = __builtin_amdgcn_mfma_f32_16x16x32_bf16(cvt8(a0, a1), cvt8(w0, w1),
                                                      acc, 0, 0, 0);
    }

    if (nt == 0) {
        ((float4*)Bpk)[((size_t)(b * LP4 + (t0 >> 2) + quad)) * NST + col] = *(float4*)&acc;
    } else if (nt == 1) {
        ((float4*)Cpk)[((size_t)(b * LP4 + (t0 >> 2) + quad)) * NST + col] = *(float4*)&acc;
    } else {            // dtp tile -> LDS: t_local = quad*4+reg, r = (nt-2)*16+col
        #pragma unroll
        for (int r = 0; r < 4; ++r)
            dtp_s[(quad * 4 + r) * 65 + (nt - 2) * 16 + col] = acc[r];
    }
    __syncthreads();

    // ---- delta GEMM: A-frag (same for all d-tiles) hoisted
    short8 da0, da1;
    #pragma unroll
    for (int j = 0; j < 8; ++j) {
        da0[j] = (short)f2bf(dtp_s[col * 65 + quad * 8 + j]);
        da1[j] = (short)f2bf(dtp_s[col * 65 + 32 + quad * 8 + j]);
    }
    for (int dt = nt; dt < 48; dt += 5) {
        const int d0 = dt * 16;
        const float* wd = Wdt + (size_t)(d0 + col) * RDT;
        const short8 b0 = cvt8(*(const float4*)(wd + quad * 8),
                               *(const float4*)(wd + quad * 8 + 4));
        short8 b1 = {};
        if (quad < 2)   // k = 32+quad*8 .. +8 valid only below 48
            b1 = cvt8(*(const float4*)(wd + 32 + quad * 8),
                      *(const float4*)(wd + 32 + quad * 8 + 4));
        float4e dacc = {};
        dacc = __builtin_amdgcn_mfma_f32_16x16x32_bf16(da0, b0, dacc, 0, 0, 0);
        dacc = __builtin_amdgcn_mfma_f32_16x16x32_bf16(da1, b1, dacc, 0, 0, 0);
        const float bb = 2.0f * bdt[d0 + col];
        float4 sp;
        {
            const float v0 = dacc[0] + bb, v1 = dacc[1] + bb;
            const float v2 = dacc[2] + bb, v3 = dacc[3] + bb;
            sp.x = (v0 > 20.f) ? v0 : __logf(1.f + __expf(v0));
            sp.y = (v1 > 20.f) ? v1 : __logf(1.f + __expf(v1));
            sp.z = (v2 > 20.f) ? v2 : __logf(1.f + __expf(v2));
            sp.w = (v3 > 20.f) ? v3 : __logf(1.f + __expf(v3));
        }
        *(float4*)(deltaT + ((size_t)(b * DIM + d0 + col)) * LSEQ + t0 + quad * 4) = sp;
    }
}

// -------- Kernel C: chunked scan (pack-trick, Kogge-Stone, DPP) ------------
// 512 thr per (b,d). 32 chunks x 16 n-lanes; chunk g owns 64 t. Phase 0
// stages delta AND dlx = delta*x (n-invariant, computed once per column —
// saves 8 muls/pack across phases). B/C/x from global with one-pack prefetch.
// Phase 3 folds +D*x, writes y straight to global (aliases xT; in-wave
// load-before-store on disjoint rows -> race-free). silu(z) in xpose_out.
__global__ __launch_bounds__(512) void scan_kernel(
        const float* __restrict__ xT, const float* __restrict__ A_log,
        const float* __restrict__ Dp,
        const float* __restrict__ Bpk, const float* __restrict__ Cpk,
        const float* __restrict__ deltaT, float* __restrict__ yv) {
    __shared__ float sdel[NCHUNK * CPAD];   // 8704 B
    __shared__ float sdlx[NCHUNK * CPAD];   // 8704 B
    __shared__ float sP[NCHUNK][NST];       // 2 KB
    __shared__ float sq[NCHUNK][NST];       // 2 KB

    const int tid = threadIdx.x;
    const int ch = blockIdx.x;           // b*768 + d
    const int b = ch / DIM;
    const int d = ch % DIM;
    const size_t row = (size_t)ch * LSEQ;

    // ---- phase 0: stage delta + delta*x (coalesced, padded chunks)
    {
        const float4 dv4 = ((const float4*)(deltaT + row))[tid];
        const float4 xv4 = ((const float4*)(xT + row))[tid];
        const int sidx = (tid >> 4) * (CPAD / 4) + (tid & 15);
        ((float4*)sdel)[sidx] = dv4;
        ((float4*)sdlx)[sidx] = make_float4(dv4.x * xv4.x, dv4.y * xv4.y,
                                            dv4.z * xv4.z, dv4.w * xv4.w);
    }
    __syncthreads();

    const int g = tid >> 4;          // chunk 0..31
    const int n = tid & 15;          // state index
    const float Aln2 = -__expf(A_log[d * NST + n]) * L2E;  // exp(x)=exp2(x*L2E)
    const float4* Bg = (const float4*)Bpk + ((size_t)(b * LP4 + g * NPACK) * NST + n);
    const float4* Cg = (const float4*)Cpk + ((size_t)(b * LP4 + g * NPACK) * NST + n);
    const float4* xr = (const float4*)(xT + row) + g * NPACK;   // broadcast (D-term)
    const float* dchunk = sdel + g * CPAD;
    const float* uchunk = sdlx + g * CPAD;

    // ---- phase 1: local scan with pack trick (chain: 1 fma per 4t)
    {
        float h = 0.f, Ptot = 1.f;
        float4 Bn_ = Bg[0];
        #pragma unroll 4
        for (int p = 0; p < NPACK; ++p) {
            const float4 B4 = Bn_;
            if (p < NPACK - 1) Bn_ = Bg[(p + 1) * NST];
            const float4 dl = *(const float4*)(dchunk + 4 * p);
            const float4 ux = *(const float4*)(uchunk + 4 * p);
            const float u0 = ux.x * B4.x, u1 = ux.y * B4.y;
            const float u2 = ux.z * B4.z, u3 = ux.w * B4.w;
            const float e0  = __builtin_amdgcn_exp2f(Aln2 * dl.x);
            const float dA1 = __builtin_amdgcn_exp2f(Aln2 * dl.y);
            const float dA2 = __builtin_amdgcn_exp2f(Aln2 * dl.z);
            const float dA3 = __builtin_amdgcn_exp2f(Aln2 * dl.w);
            float s = u0;
            s = fmaf(dA1, s, u1); s = fmaf(dA2, s, u2); s = fmaf(dA3, s, u3);
            const float E3 = ((e0 * dA1) * (dA2 * dA3));
            h = fmaf(E3, h, s);          // the only cross-pack chain op
            Ptot *= E3;
        }
        sP[g][n] = Ptot;
        sq[g][n] = h;
    }
    __syncthreads();

    // ---- phase 2: Kogge-Stone inclusive scan over 32 chunks (5 steps)
    {
        float Pc = sP[g][n], qc = sq[g][n];
        #pragma unroll
        for (int s = 1; s < NCHUNK; s <<= 1) {
            float Pp = 1.f, qp = 0.f;
            if (g >= s) { Pp = sP[g - s][n]; qp = sq[g - s][n]; }
            __syncthreads();
            qc = fmaf(Pc, qp, qc);
            Pc *= Pp;
            sP[g][n] = Pc; sq[g][n] = qc;
            __syncthreads();
        }
    }

    // ---- phase 3: re-scan with carry; DPP n-reduction; y -> global (+D*x)
    {
        float h = (g == 0) ? 0.f : sq[g - 1][n];
        const float Dd = Dp[d];
        float4 Bn_ = Bg[0], Cn_ = Cg[0], xn_ = xr[0];
        #pragma unroll 4
        for (int p = 0; p < NPACK; ++p) {
            const float4 B4 = Bn_, C4 = Cn_, x4 = xn_;
            if (p < NPACK - 1) { Bn_ = Bg[(p + 1) * NST]; Cn_ = Cg[(p + 1) * NST]; xn_ = xr[p + 1]; }
            const float4 dl = *(const float4*)(dchunk + 4 * p);
            const float4 ux = *(const float4*)(uchunk + 4 * p);
            const float u0 = ux.x * B4.x, u1 = ux.y * B4.y;
            const float u2 = ux.z * B4.z, u3 = ux.w * B4.w;
            const float E0  = __builtin_amdgcn_exp2f(Aln2 * dl.x);
            const float dA1 = __builtin_amdgcn_exp2f(Aln2 * dl.y);
            const float dA2 = __builtin_amdgcn_exp2f(Aln2 * dl.z);
            const float dA3 = __builtin_amdgcn_exp2f(Aln2 * dl.w);
            const float E1 = E0 * dA1, E2 = E1 * dA2, E3 = E2 * dA3;
            const float s0 = u0;
            const float s1 = fmaf(dA1, s0, u1);
            const float s2 = fmaf(dA2, s1, u2);
            const float s3 = fmaf(dA3, s2, u3);
            const float h0 = fmaf(E0, h, s0);
            const float h1 = fmaf(E1, h, s1);
            const float h2 = fmaf(E2, h, s2);
            const float h3 = fmaf(E3, h, s3);
            h = h3;                      // 1-fma cross-pack chain
            float p0 = h0 * C4.x, p1 = h1 * C4.y, p2 = h2 * C4.z, p3 = h3 * C4.w;
            p0 = dpp_add<0xB1>(p0); p0 = dpp_add<0x4E>(p0);   // quad sums
            p1 = dpp_add<0xB1>(p1); p1 = dpp_add<0x4E>(p1);
            p2 = dpp_add<0xB1>(p2); p2 = dpp_add<0x4E>(p2);
            p3 = dpp_add<0xB1>(p3); p3 = dpp_add<0x4E>(p3);
            float v = (n & 1) ? ((n & 2) ? p3 : p1) : ((n & 2) ? p2 : p0);
            v = dpp_add<0x124>(v);       // row_ror:4
            v = dpp_add<0x128>(v);       // row_ror:8
            if (n < 4) {                 // lane n holds total for t = 4p+n
                const float xc = (n == 0) ? x4.x : (n == 1) ? x4.y : (n == 2) ? x4.z : x4.w;
                yv[row + g * CLEN + 4 * p + n] = fmaf(xc, Dd, v);
            }
        }
    }
}

// -------- Kernel T: output transpose + silu(z) epilogue --------------------
// yv and z are both (b,d,l); out = yv * z*sigmoid(z), transposed to (b,l,d).
__global__ __launch_bounds__(256) void xpose_out_kernel(
        const float* __restrict__ yv, const float* __restrict__ z,
        float* __restrict__ out) {
    __shared__ float tile[64 * 65];   // transposed: tile[l][d]
    const int r0 = blockIdx.x * 64;   // d
    const int c0 = blockIdx.y * 64;   // l
    const int b  = blockIdx.z;
    const int tid = threadIdx.x;
    {
        const int c4 = tid & 15, rb = tid >> 4;
        #pragma unroll
        for (int rr = 0; rr < 4; ++rr) {
            const int row = rr * 16 + rb;
            const size_t gidx = ((size_t)b * DIM + r0 + row) * LSEQ + c0 + c4 * 4;
            const float4 v = *(const float4*)(yv + gidx);
            const float4 zv = *(const float4*)(z + gidx);
            tile[(c4 * 4 + 0) * 65 + row] = v.x * zv.x / (1.f + __expf(-zv.x));
            tile[(c4 * 4 + 1) * 65 + row] = v.y * zv.y / (1.f + __expf(-zv.y));
            tile[(c4 * 4 + 2) * 65 + row] = v.z * zv.z / (1.f + __expf(-zv.z));
            tile[(c4 * 4 + 3) * 65 + row] = v.w * zv.w / (1.f + __expf(-zv.w));
        }
    }
    __syncthreads();
    {
        const int t4 = tid & 15, dq = tid >> 4;
        #pragma unroll
        for (int pass = 0; pass < 4; ++pass) {
            const int ll = pass * 16 + dq;
            float4 v;
            v.x = tile[ll * 65 + t4 * 4 + 0];
            v.y = tile[ll * 65 + t4 * 4 + 1];
            v.z = tile[ll * 65 + t4 * 4 + 2];
            v.w = tile[ll * 65 + t4 * 4 + 3];
            *(float4*)(out + ((size_t)b * LSEQ + c0 + ll) * DIM + r0 + t4 * 4) = v;
        }
    }
}

extern "C" void kernel_launch(void* const* d_in, const int* in_sizes, int n_in,
                              void* d_out, int out_size, void* d_ws, size_t ws_size,
                              hipStream_t stream) {
    const float* x     = (const float*)d_in[0];  // (2,2048,768)
    const float* z     = (const float*)d_in[1];  // (2,768,2048)
    const float* A_log = (const float*)d_in[2];  // (768,16)
    const float* D     = (const float*)d_in[3];  // (768,)
    const float* Wx    = (const float*)d_in[4];  // (1680,768)
    const float* Wdt   = (const float*)d_in[5];  // (768,48)
    const float* bdt   = (const float*)d_in[6];  // (768,)
    float* out = (float*)d_out;

    // ws layout (floats): Bpk | Cpk | deltaT | xT (scan writes yv over it)
    float* ws     = (float*)d_ws;
    float* Bpk    = ws;
    float* Cpk    = Bpk + (size_t)BATCH * LP4 * NST * 4;
    float* deltaT = Cpk + (size_t)BATCH * LP4 * NST * 4;
    float* xT     = deltaT + (size_t)BATCH * DIM * LSEQ;
    float* yv     = xT;   // alias: in-wave load-before-store, rows disjoint per block

    hipLaunchKernelGGL(proj_gemm_kernel, dim3(BL / 16), dim3(320), 0, stream,
                       x, Wx, Wdt, bdt, Bpk, Cpk, deltaT, xT);
    hipLaunchKernelGGL(scan_kernel, dim3(BATCH * DIM), dim3(512), 0, stream,
                       xT, A_log, D, Bpk, Cpk, deltaT, yv);
    hipLaunchKernelGGL(xpose_out_kernel, dim3(DIM / 64, LSEQ / 64, BATCH), dim3(256), 0, stream,
                       yv, z, out);
}

// Round 13
// 144.596 us; speedup vs baseline: 1.1424x; 1.0210x over previous
//
#include <hip/hip_runtime.h>
#include <math.h>

// Problem constants (S4Checkpointed): b=2, L=2048, d=768, n=16, r=48
#define BATCH 2
#define LSEQ  2048
#define DIM   768
#define NST   16
#define RDT   48
#define BL    (BATCH*LSEQ)   // 4096
#define NCHUNK 32
#define CLEN   (LSEQ/NCHUNK) // 64
#define CPAD   68            // chunk stride floats: 68%32==4 -> wave's 4 groups on distinct banks
#define NPACK  (CLEN/4)      // 16 float4 packs per chunk
#define LP4    (LSEQ/4)      // 512 t-packs per (b)
#define L2E    1.4426950408889634f

typedef __attribute__((ext_vector_type(8))) short short8;     // 8 bf16 (4 VGPRs)
typedef __attribute__((ext_vector_type(4))) float float4e;    // MFMA acc

// bf16 pack via v_perm_b32: 2 adds + 1 perm per 2 values (round-half-up).
// perm(s0=ub, s1=ua, 0x07060302): dst = ua.b[3:2] | ub.b[3:2]<<16.
__device__ __forceinline__ unsigned bfpk(float a, float b) {
    const unsigned ua = __float_as_uint(a) + 0x8000u;
    const unsigned ub = __float_as_uint(b) + 0x8000u;
    return __builtin_amdgcn_perm(ub, ua, 0x07060302u);
}
__device__ __forceinline__ short8 pk8(float4 a, float4 b) {
    union { unsigned u[4]; short8 s; } r;
    r.u[0] = bfpk(a.x, a.y);
    r.u[1] = bfpk(a.z, a.w);
    r.u[2] = bfpk(b.x, b.y);
    r.u[3] = bfpk(b.z, b.w);
    return r.s;
}

// DPP cross-lane add on the VALU pipe (no ds_swizzle).
// 0xB1 = quad_perm xor1; 0x4E = quad_perm xor2; 0x124/0x128 = row_ror:4/8
// (rotation mod 16 preserves n&3 -> exact for our 16-lane row sum).
template <int CTRL>
__device__ __forceinline__ float dpp_add(float v) {
    const int s = __builtin_amdgcn_update_dpp(__float_as_int(v), __float_as_int(v),
                                              CTRL, 0xF, 0xF, false);
    return v + __int_as_float(s);
}

// -------- Kernel G: proj GEMM + delta GEMM + xT emit (MFMA, K-split x2) ----
// Block = 10 waves (640 thr), one 16-row bl-tile. Pass 1: proj (M=16, N=80,
// K=768) with K split in half across wave-pairs: wave w = half*5+nt does
// K[half*384 : half*384+384] of N-tile nt; partials merged via LDS (fp32 add).
// xT emit spread over all 10 waves (each emits kk's it already loads).
// Pass 2: delta GEMM (M=16 t, N=768 d, K=48) round-robin over 10 waves;
// softplus(. + 2*bdt) -> deltaT (b,d,l) coalesced.
__global__ __launch_bounds__(640) void proj_gemm_kernel(
        const float* __restrict__ x, const float* __restrict__ Wx,
        const float* __restrict__ Wdt, const float* __restrict__ bdt,
        float* __restrict__ Bpk, float* __restrict__ Cpk,
        float* __restrict__ deltaT, float* __restrict__ xT) {
    __shared__ float dtp_s[16 * 65];     // [t][r], stride 65; cols 48..63 stay 0
    __shared__ float4 red_s[5 * 64];     // upper-half partial accs (5 KB)
    const int m0   = blockIdx.x * 16;    // bl tile base (never straddles b)
    const int w    = threadIdx.x >> 6;   // 0..9
    const int half = (w >= 5) ? 1 : 0;
    const int nt   = w - half * 5;       // N-tile 0..4
    const int lane = threadIdx.x & 63;
    const int col  = lane & 15;
    const int quad = lane >> 4;
    const int b  = m0 >> 11;
    const int t0 = m0 & 2047;

    for (int i = threadIdx.x; i < 16 * 65; i += 640) dtp_s[i] = 0.f;
    __syncthreads();

    const int j80  = nt * 16 + col;      // 0..79
    const int wrow = (j80 < 16) ? j80 : ((j80 < 32) ? (j80 + 16) : (j80 + 1552));
    const float* A  = x + (size_t)(m0 + col) * DIM + quad * 8;
    const float* Wr = Wx + (size_t)wrow * DIM + quad * 8;

    const int kbase = half * 12;
    const int kklo  = kbase + (nt * 12) / 5;        // xT emit share (within half)
    const int kkhi  = kbase + ((nt + 1) * 12) / 5;

    float4e acc = {};
    #pragma unroll 4
    for (int kk2 = 0; kk2 < 12; ++kk2) {
        const int kk = kbase + kk2;
        const float4 a0 = *(const float4*)(A + kk * 32);
        const float4 a1 = *(const float4*)(A + kk * 32 + 4);
        if (kk >= kklo && kk < kkhi) {   // emit xT: 16 lanes span 16 consecutive t
            const int dbase = kk * 32 + quad * 8;
            float* xc = xT + ((size_t)(b * DIM + dbase)) * LSEQ + t0 + col;
            xc[0 * LSEQ] = a0.x; xc[1 * LSEQ] = a0.y;
            xc[2 * LSEQ] = a0.z; xc[3 * LSEQ] = a0.w;
            xc[4 * LSEQ] = a1.x; xc[5 * LSEQ] = a1.y;
            xc[6 * LSEQ] = a1.z; xc[7 * LSEQ] = a1.w;
        }
        const float4 w0 = *(const float4*)(Wr + kk * 32);
        const float4 w1 = *(const float4*)(Wr + kk * 32 + 4);
        acc = __builtin_amdgcn_mfma_f32_16x16x32_bf16(pk8(a0, a1), pk8(w0, w1),
                                                      acc, 0, 0, 0);
    }

    if (half) {                          // upper half: stash partials
        red_s[nt * 64 + lane] = make_float4(acc[0], acc[1], acc[2], acc[3]);
    }
    __syncthreads();
    if (!half) {                         // lower half: merge + store
        const float4 o = red_s[nt * 64 + lane];
        acc[0] += o.x; acc[1] += o.y; acc[2] += o.z; acc[3] += o.w;
        if (nt == 0) {
            ((float4*)Bpk)[((size_t)(b * LP4 + (t0 >> 2) + quad)) * NST + col] = *(float4*)&acc;
        } else if (nt == 1) {
            ((float4*)Cpk)[((size_t)(b * LP4 + (t0 >> 2) + quad)) * NST + col] = *(float4*)&acc;
        } else {        // dtp tile -> LDS: t_local = quad*4+reg, r = (nt-2)*16+col
            #pragma unroll
            for (int r = 0; r < 4; ++r)
                dtp_s[(quad * 4 + r) * 65 + (nt - 2) * 16 + col] = acc[r];
        }
    }
    __syncthreads();

    // ---- delta GEMM: A-frag (same for all d-tiles) hoisted; 10-way round-robin
    short8 da0, da1;
    {
        union { unsigned u[4]; short8 s; } r0, r1;
        const float* base = dtp_s + col * 65 + quad * 8;
        #pragma unroll
        for (int j = 0; j < 2; ++j) {
            r0.u[2 * j]     = bfpk(base[4 * j], base[4 * j + 1]);
            r0.u[2 * j + 1] = bfpk(base[4 * j + 2], base[4 * j + 3]);
            r1.u[2 * j]     = bfpk(base[32 + 4 * j], base[32 + 4 * j + 1]);
            r1.u[2 * j + 1] = bfpk(base[32 + 4 * j + 2], base[32 + 4 * j + 3]);
        }
        da0 = r0.s; da1 = r1.s;
    }
    for (int dt = w; dt < 48; dt += 10) {
        const int d0 = dt * 16;
        const float* wd = Wdt + (size_t)(d0 + col) * RDT;
        const short8 b0 = pk8(*(const float4*)(wd + quad * 8),
                              *(const float4*)(wd + quad * 8 + 4));
        short8 b1 = {};
        if (quad < 2)   // k = 32+quad*8 .. +8 valid only below 48
            b1 = pk8(*(const float4*)(wd + 32 + quad * 8),
                     *(const float4*)(wd + 32 + quad * 8 + 4));
        float4e dacc = {};
        dacc = __builtin_amdgcn_mfma_f32_16x16x32_bf16(da0, b0, dacc, 0, 0, 0);
        dacc = __builtin_amdgcn_mfma_f32_16x16x32_bf16(da1, b1, dacc, 0, 0, 0);
        const float bb = 2.0f * bdt[d0 + col];
        float4 sp;
        {
            const float v0 = dacc[0] + bb, v1 = dacc[1] + bb;
            const float v2 = dacc[2] + bb, v3 = dacc[3] + bb;
            sp.x = (v0 > 20.f) ? v0 : __logf(1.f + __expf(v0));
            sp.y = (v1 > 20.f) ? v1 : __logf(1.f + __expf(v1));
            sp.z = (v2 > 20.f) ? v2 : __logf(1.f + __expf(v2));
            sp.w = (v3 > 20.f) ? v3 : __logf(1.f + __expf(v3));
        }
        *(float4*)(deltaT + ((size_t)(b * DIM + d0 + col)) * LSEQ + t0 + quad * 4) = sp;
    }
}

// -------- Kernel C: chunked scan (pack-trick, Kogge-Stone, DPP) ------------
// 512 thr per (b,d). 32 chunks x 16 n-lanes; chunk g owns 64 t. Phase 0
// stages delta AND dlx = delta*x (n-invariant). B/C/x from global with
// one-pack prefetch. Phase 3 folds +D*x, writes y straight to global
// (aliases xT; in-wave load-before-store on disjoint rows -> race-free).
// silu(z) applied in xpose_out.
__global__ __launch_bounds__(512) void scan_kernel(
        const float* __restrict__ xT, const float* __restrict__ A_log,
        const float* __restrict__ Dp,
        const float* __restrict__ Bpk, const float* __restrict__ Cpk,
        const float* __restrict__ deltaT, float* __restrict__ yv) {
    __shared__ float sdel[NCHUNK * CPAD];   // 8704 B
    __shared__ float sdlx[NCHUNK * CPAD];   // 8704 B
    __shared__ float sP[NCHUNK][NST];       // 2 KB
    __shared__ float sq[NCHUNK][NST];       // 2 KB

    const int tid = threadIdx.x;
    const int ch = blockIdx.x;           // b*768 + d
    const int b = ch / DIM;
    const int d = ch % DIM;
    const size_t row = (size_t)ch * LSEQ;

    // ---- phase 0: stage delta + delta*x (coalesced, padded chunks)
    {
        const float4 dv4 = ((const float4*)(deltaT + row))[tid];
        const float4 xv4 = ((const float4*)(xT + row))[tid];
        const int sidx = (tid >> 4) * (CPAD / 4) + (tid & 15);
        ((float4*)sdel)[sidx] = dv4;
        ((float4*)sdlx)[sidx] = make_float4(dv4.x * xv4.x, dv4.y * xv4.y,
                                            dv4.z * xv4.z, dv4.w * xv4.w);
    }
    __syncthreads();

    const int g = tid >> 4;          // chunk 0..31
    const int n = tid & 15;          // state index
    const float Aln2 = -__expf(A_log[d * NST + n]) * L2E;  // exp(x)=exp2(x*L2E)
    const float4* Bg = (const float4*)Bpk + ((size_t)(b * LP4 + g * NPACK) * NST + n);
    const float4* Cg = (const float4*)Cpk + ((size_t)(b * LP4 + g * NPACK) * NST + n);
    const float4* xr = (const float4*)(xT + row) + g * NPACK;   // broadcast (D-term)
    const float* dchunk = sdel + g * CPAD;
    const float* uchunk = sdlx + g * CPAD;

    // ---- phase 1: local scan with pack trick (chain: 1 fma per 4t)
    {
        float h = 0.f, Ptot = 1.f;
        float4 Bn_ = Bg[0];
        #pragma unroll 4
        for (int p = 0; p < NPACK; ++p) {
            const float4 B4 = Bn_;
            if (p < NPACK - 1) Bn_ = Bg[(p + 1) * NST];
            const float4 dl = *(const float4*)(dchunk + 4 * p);
            const float4 ux = *(const float4*)(uchunk + 4 * p);
            const float u0 = ux.x * B4.x, u1 = ux.y * B4.y;
            const float u2 = ux.z * B4.z, u3 = ux.w * B4.w;
            const float e0  = __builtin_amdgcn_exp2f(Aln2 * dl.x);
            const float dA1 = __builtin_amdgcn_exp2f(Aln2 * dl.y);
            const float dA2 = __builtin_amdgcn_exp2f(Aln2 * dl.z);
            const float dA3 = __builtin_amdgcn_exp2f(Aln2 * dl.w);
            float s = u0;
            s = fmaf(dA1, s, u1); s = fmaf(dA2, s, u2); s = fmaf(dA3, s, u3);
            const float E3 = ((e0 * dA1) * (dA2 * dA3));
            h = fmaf(E3, h, s);          // the only cross-pack chain op
            Ptot *= E3;
        }
        sP[g][n] = Ptot;
        sq[g][n] = h;
    }
    __syncthreads();

    // ---- phase 2: Kogge-Stone inclusive scan over 32 chunks (5 steps)
    {
        float Pc = sP[g][n], qc = sq[g][n];
        #pragma unroll
        for (int s = 1; s < NCHUNK; s <<= 1) {
            float Pp = 1.f, qp = 0.f;
            if (g >= s) { Pp = sP[g - s][n]; qp = sq[g - s][n]; }
            __syncthreads();
            qc = fmaf(Pc, qp, qc);
            Pc *= Pp;
            sP[g][n] = Pc; sq[g][n] = qc;
            __syncthreads();
        }
    }

    // ---- phase 3: re-scan with carry; DPP n-reduction; y -> global (+D*x)
    {
        float h = (g == 0) ? 0.f : sq[g - 1][n];
        const float Dd = Dp[d];
        float4 Bn_ = Bg[0], Cn_ = Cg[0], xn_ = xr[0];
        #pragma unroll 4
        for (int p = 0; p < NPACK; ++p) {
            const float4 B4 = Bn_, C4 = Cn_, x4 = xn_;
            if (p < NPACK - 1) { Bn_ = Bg[(p + 1) * NST]; Cn_ = Cg[(p + 1) * NST]; xn_ = xr[p + 1]; }
            const float4 dl = *(const float4*)(dchunk + 4 * p);
            const float4 ux = *(const float4*)(uchunk + 4 * p);
            const float u0 = ux.x * B4.x, u1 = ux.y * B4.y;
            const float u2 = ux.z * B4.z, u3 = ux.w * B4.w;
            const float E0  = __builtin_amdgcn_exp2f(Aln2 * dl.x);
            const float dA1 = __builtin_amdgcn_exp2f(Aln2 * dl.y);
            const float dA2 = __builtin_amdgcn_exp2f(Aln2 * dl.z);
            const float dA3 = __builtin_amdgcn_exp2f(Aln2 * dl.w);
            const float E1 = E0 * dA1, E2 = E1 * dA2, E3 = E2 * dA3;
            const float s0 = u0;
            const float s1 = fmaf(dA1, s0, u1);
            const float s2 = fmaf(dA2, s1, u2);
            const float s3 = fmaf(dA3, s2, u3);
            const float h0 = fmaf(E0, h, s0);
            const float h1 = fmaf(E1, h, s1);
            const float h2 = fmaf(E2, h, s2);
            const float h3 = fmaf(E3, h, s3);
            h = h3;                      // 1-fma cross-pack chain
            float p0 = h0 * C4.x, p1 = h1 * C4.y, p2 = h2 * C4.z, p3 = h3 * C4.w;
            p0 = dpp_add<0xB1>(p0); p0 = dpp_add<0x4E>(p0);   // quad sums
            p1 = dpp_add<0xB1>(p1); p1 = dpp_add<0x4E>(p1);
            p2 = dpp_add<0xB1>(p2); p2 = dpp_add<0x4E>(p2);
            p3 = dpp_add<0xB1>(p3); p3 = dpp_add<0x4E>(p3);
            float v = (n & 1) ? ((n & 2) ? p3 : p1) : ((n & 2) ? p2 : p0);
            v = dpp_add<0x124>(v);       // row_ror:4
            v = dpp_add<0x128>(v);       // row_ror:8
            if (n < 4) {                 // lane n holds total for t = 4p+n
                const float xc = (n == 0) ? x4.x : (n == 1) ? x4.y : (n == 2) ? x4.z : x4.w;
                yv[row + g * CLEN + 4 * p + n] = fmaf(xc, Dd, v);
            }
        }
    }
}

// -------- Kernel T: output transpose + silu(z) epilogue --------------------
// yv and z are both (b,d,l); out = yv * z*sigmoid(z), transposed to (b,l,d).
__global__ __launch_bounds__(256) void xpose_out_kernel(
        const float* __restrict__ yv, const float* __restrict__ z,
        float* __restrict__ out) {
    __shared__ float tile[64 * 65];   // transposed: tile[l][d]
    const int r0 = blockIdx.x * 64;   // d
    const int c0 = blockIdx.y * 64;   // l
    const int b  = blockIdx.z;
    const int tid = threadIdx.x;
    {
        const int c4 = tid & 15, rb = tid >> 4;
        #pragma unroll
        for (int rr = 0; rr < 4; ++rr) {
            const int row = rr * 16 + rb;
            const size_t gidx = ((size_t)b * DIM + r0 + row) * LSEQ + c0 + c4 * 4;
            const float4 v = *(const float4*)(yv + gidx);
            const float4 zv = *(const float4*)(z + gidx);
            tile[(c4 * 4 + 0) * 65 + row] = v.x * zv.x / (1.f + __expf(-zv.x));
            tile[(c4 * 4 + 1) * 65 + row] = v.y * zv.y / (1.f + __expf(-zv.y));
            tile[(c4 * 4 + 2) * 65 + row] = v.z * zv.z / (1.f + __expf(-zv.z));
            tile[(c4 * 4 + 3) * 65 + row] = v.w * zv.w / (1.f + __expf(-zv.w));
        }
    }
    __syncthreads();
    {
        const int t4 = tid & 15, dq = tid >> 4;
        #pragma unroll
        for (int pass = 0; pass < 4; ++pass) {
            const int ll = pass * 16 + dq;
            float4 v;
            v.x = tile[ll * 65 + t4 * 4 + 0];
            v.y = tile[ll * 65 + t4 * 4 + 1];
            v.z = tile[ll * 65 + t4 * 4 + 2];
            v.w = tile[ll * 65 + t4 * 4 + 3];
            *(float4*)(out + ((size_t)b * LSEQ + c0 + ll) * DIM + r0 + t4 * 4) = v;
        }
    }
}

extern "C" void kernel_launch(void* const* d_in, const int* in_sizes, int n_in,
                              void* d_out, int out_size, void* d_ws, size_t ws_size,
                              hipStream_t stream) {
    const float* x     = (const float*)d_in[0];  // (2,2048,768)
    const float* z     = (const float*)d_in[1];  // (2,768,2048)
    const float* A_log = (const float*)d_in[2];  // (768,16)
    const float* D     = (const float*)d_in[3];  // (768,)
    const float* Wx    = (const float*)d_in[4];  // (1680,768)
    const float* Wdt   = (const float*)d_in[5];  // (768,48)
    const float* bdt   = (const float*)d_in[6];  // (768,)
    float* out = (float*)d_out;

    // ws layout (floats): Bpk | Cpk | deltaT | xT (scan writes yv over it)
    float* ws     = (float*)d_ws;
    float* Bpk    = ws;
    float* Cpk    = Bpk + (size_t)BATCH * LP4 * NST * 4;
    float* deltaT = Cpk + (size_t)BATCH * LP4 * NST * 4;
    float* xT     = deltaT + (size_t)BATCH * DIM * LSEQ;
    float* yv     = xT;   // alias: in-wave load-before-store, rows disjoint per block

    hipLaunchKernelGGL(proj_gemm_kernel, dim3(BL / 16), dim3(640), 0, stream,
                       x, Wx, Wdt, bdt, Bpk, Cpk, deltaT, xT);
    hipLaunchKernelGGL(scan_kernel, dim3(BATCH * DIM), dim3(512), 0, stream,
                       xT, A_log, D, Bpk, Cpk, deltaT, yv);
    hipLaunchKernelGGL(xpose_out_kernel, dim3(DIM / 64, LSEQ / 64, BATCH), dim3(256), 0, stream,
                       yv, z, out);
}